// Round 6
// baseline (310.378 us; speedup 1.0000x reference)
//
#include <hip/hip_runtime.h>

// CapsuleNetwork routing, fused, one block per batch. B=2048, S=200, D=64, K=4.
//
// hat[b,k,s,:] = emb[b,s,:] @ W_k + b_k is never materialized:
//   logits[k,s] = emb[s]·u[k] + off[k],  u[k] = W_k @ G[k], off[k] = b_k·G[k]
//   v[k]        = e[k] @ W_k + ts[k]·b_k, e[k] = sum_s sw[k,s] emb[s]
// G = running sum of interests (cw telescopes).
//
// Round-6 = round-4 structure (wreg W-cache, standalone phase A — the 96.8us
// config; round 5 proved W global reads in the hot loop thrash L2: FETCH
// 53->398MB) + round-5 mask compaction (sw==0 rows contribute nothing; stage
// only ~100 active rows -> B/D work halves, LDS 51.9KB -> 3 blocks/CU)
// + rot(i)=(i+(i>>4))&15 chunk rotation (kills B's 4-way bank conflict)
// + per-wave-half pe reduce (one less barrier).

#define NB 2048
#define NS 200
#define ND 64
#define NK 4
#define NT 512
#define CAP 140  // LDS-staged active rows; >CAP handled from global (P~1e-5)

__device__ __forceinline__ float wred64(float v) {
#pragma unroll
  for (int o = 1; o < 64; o <<= 1) v += __shfl_xor(v, o, 64);
  return v;
}

__device__ __forceinline__ int rot(int i) { return (i + (i >> 4)) & 15; }

__device__ __forceinline__ void gload16(const float* g_, float* l_) {
  __builtin_amdgcn_global_load_lds(
      (const __attribute__((address_space(1))) unsigned int*)g_,
      (__attribute__((address_space(3))) unsigned int*)l_, 16, 0, 0);
}

#define RED_GRP(v) v += __shfl_xor(v, 16, 64); v += __shfl_xor(v, 32, 64);

__global__ __launch_bounds__(NT, 4) void caps_kernel(
    const float* __restrict__ his, const float* __restrict__ itemeb,
    const int* __restrict__ mask, const float* __restrict__ W,
    const float* __restrict__ bias, float* __restrict__ out) {
  __shared__ float semb[(CAP + 4) * ND];  // 36864B: compact row i, chunk c at
                                          // slot (c + rot(i)) & 15
  __shared__ float ssw4[NS * NK];         // sw[i][k] by compact index
  __shared__ float pe[8][NK][ND];         // per-wave D partials
  __shared__ float se[NK][ND];            // reduced e[k] (bounce buffer)
  __shared__ float pv[NK][ND];            // E h1 partials; interest stash
  __shared__ float sG[NK][ND];            // running interest sum
  __shared__ float su[NK][ND];            // u[k]
  __shared__ unsigned short sidxs[NS];    // compact index -> original s
  __shared__ int swofs[8];
  __shared__ float pts[8][NK];
  __shared__ float soff[NK], satt[NK];
  __shared__ int sidx;

  const int t = threadIdx.x;
  const int w = t >> 6, l = t & 63;
  const int g = l >> 4, j = l & 15;  // 16-lane group / chunk
  const int gid = (w << 2) | g;      // 0..31
  const int k_ = w & 3, h_ = w >> 2;
  const int b = blockIdx.x;
  const float* eb = his + (size_t)b * NS * ND;

  // ---- compaction: active-row list via ballot prefix ----
  int m = (t < NS) ? (mask[b * NS + t] != 0) : 0;
  unsigned long long bal = __ballot(m);
  int pre = __popcll(bal & ((1ull << l) - 1));
  if (l == 0) swofs[w] = __popcll(bal);
  float breg = bias[k_ * ND + l];
  float iq = itemeb[(size_t)b * ND + l];
  __syncthreads();
  int base = 0, nact = 0;
#pragma unroll
  for (int ww = 0; ww < 8; ++ww) {
    base += (ww < w) ? swofs[ww] : 0;
    nact += swofs[ww];
  }
  if (m) sidxs[base + pre] = (unsigned short)t;
  __syncthreads();
  const int ncore = nact < CAP ? nact : CAP;

  // ---- W slice cached in regs: wave (k,h) owns W[32h..32h+32][64k+l] ----
  float wreg[32];
#pragma unroll
  for (int c = 0; c < 32; ++c)
    wreg[c] = W[(size_t)(32 * h_ + c) * (NK * ND) + k_ * ND + l];

  // ---- stage active rows (linear LDS dest, rotated global source) ----
  for (int i4 = w; 4 * i4 < ncore; i4 += 8) {
    int i = 4 * i4 + g;
    int ii = (i < ncore) ? i : (ncore - 1);  // dup tail, never read
    int s = sidxs[ii];
    int q = (j - rot(i)) & 15;
    gload16(eb + (s << 6) + (q << 2), &semb[i4 * 256]);
  }
  __syncthreads();

  for (int it = 0; it < 3; ++it) {
    if (it > 0) {
      // ---- A: waves 0-3: su[w][c=l] = W-row-l(cols 64w..) . G[w];
      //         waves 4-7: soff[w-4] = b . G ----
      if (w < 4) {
        const float4* Wr = (const float4*)(W + (size_t)l * (NK * ND) + w * ND);
        const float4* Gk = (const float4*)&sG[w][0];  // broadcast
        float a = 0.f;
#pragma unroll
        for (int d4 = 0; d4 < 16; ++d4) {
          float4 wv = Wr[d4], gv = Gk[d4];
          a += wv.x * gv.x + wv.y * gv.y + wv.z * gv.z + wv.w * gv.w;
        }
        su[w][l] = a;
      } else {
        float ob = wred64(breg * sG[w - 4][l]);  // breg IS bias[(w-4)*64+l]
        if (l == 0) soff[w - 4] = ob;
      }
      __syncthreads();

      // ---- B: thread-per-compact-row; in-lane softmax over k ----
      if (t < ncore) {
        int rt = rot(t);
        float lg0 = soff[0], lg1 = soff[1], lg2 = soff[2], lg3 = soff[3];
#pragma unroll
        for (int jj = 0; jj < 16; ++jj) {
          float4 eq = *(const float4*)&semb[(t << 6) + 4 * ((jj + rt) & 15)];
          float4 u0 = *(const float4*)&su[0][4 * jj];  // broadcast reads
          float4 u1 = *(const float4*)&su[1][4 * jj];
          float4 u2 = *(const float4*)&su[2][4 * jj];
          float4 u3 = *(const float4*)&su[3][4 * jj];
          lg0 += eq.x * u0.x + eq.y * u0.y + eq.z * u0.z + eq.w * u0.w;
          lg1 += eq.x * u1.x + eq.y * u1.y + eq.z * u1.z + eq.w * u1.w;
          lg2 += eq.x * u2.x + eq.y * u2.y + eq.z * u2.z + eq.w * u2.w;
          lg3 += eq.x * u3.x + eq.y * u3.y + eq.z * u3.z + eq.w * u3.w;
        }
        float mx = fmaxf(fmaxf(lg0, lg1), fmaxf(lg2, lg3));
        float e0 = __expf(lg0 - mx), e1 = __expf(lg1 - mx);
        float e2 = __expf(lg2 - mx), e3 = __expf(lg3 - mx);
        float r = 1.0f / (e0 + e1 + e2 + e3);  // all staged rows are active
        *(float4*)&ssw4[t * 4] = make_float4(e0 * r, e1 * r, e2 * r, e3 * r);
      }
      // rare epilogue: active rows beyond CAP, straight from global
      for (int i = CAP + t; i < nact; i += NT) {
        int s = sidxs[i];
        const float4* er = (const float4*)(eb + (s << 6));
        float lg0 = soff[0], lg1 = soff[1], lg2 = soff[2], lg3 = soff[3];
#pragma unroll
        for (int jj = 0; jj < 16; ++jj) {
          float4 eq = er[jj];
          float4 u0 = *(const float4*)&su[0][4 * jj];
          float4 u1 = *(const float4*)&su[1][4 * jj];
          float4 u2 = *(const float4*)&su[2][4 * jj];
          float4 u3 = *(const float4*)&su[3][4 * jj];
          lg0 += eq.x * u0.x + eq.y * u0.y + eq.z * u0.z + eq.w * u0.w;
          lg1 += eq.x * u1.x + eq.y * u1.y + eq.z * u1.z + eq.w * u1.w;
          lg2 += eq.x * u2.x + eq.y * u2.y + eq.z * u2.z + eq.w * u2.w;
          lg3 += eq.x * u3.x + eq.y * u3.y + eq.z * u3.z + eq.w * u3.w;
        }
        float mx = fmaxf(fmaxf(lg0, lg1), fmaxf(lg2, lg3));
        float e0 = __expf(lg0 - mx), e1 = __expf(lg1 - mx);
        float e2 = __expf(lg2 - mx), e3 = __expf(lg3 - mx);
        float r = 1.0f / (e0 + e1 + e2 + e3);
        *(float4*)&ssw4[i * 4] = make_float4(e0 * r, e1 * r, e2 * r, e3 * r);
      }
      __syncthreads();
    }

    // ---- D: group gid sweeps compact rows i = gid + 32t; lane j = chunk j
    float4 a0 = {0, 0, 0, 0}, a1 = {0, 0, 0, 0}, a2 = {0, 0, 0, 0},
           a3 = {0, 0, 0, 0};
    float t0 = 0, t1 = 0, t2 = 0, t3 = 0;
    for (int i = gid; i < ncore; i += 32) {
      float4 eq = *(const float4*)&semb[(i << 6) + 4 * ((j + rot(i)) & 15)];
      if (it == 0) {
        a0.x += eq.x; a0.y += eq.y; a0.z += eq.z; a0.w += eq.w;
        t0 += 1.0f;
      } else {
        float4 s4 = *(const float4*)&ssw4[i * 4];  // broadcast
        a0.x += s4.x * eq.x; a0.y += s4.x * eq.y; a0.z += s4.x * eq.z; a0.w += s4.x * eq.w;
        a1.x += s4.y * eq.x; a1.y += s4.y * eq.y; a1.z += s4.y * eq.z; a1.w += s4.y * eq.w;
        a2.x += s4.z * eq.x; a2.y += s4.z * eq.y; a2.z += s4.z * eq.z; a2.w += s4.z * eq.w;
        a3.x += s4.w * eq.x; a3.y += s4.w * eq.y; a3.z += s4.w * eq.z; a3.w += s4.w * eq.w;
        t0 += s4.x; t1 += s4.y; t2 += s4.z; t3 += s4.w;
      }
    }
    for (int i = CAP + gid; i < nact; i += 32) {  // rare global epilogue
      int s = sidxs[i];
      float4 eq = *(const float4*)&eb[(s << 6) + 4 * j];
      if (it == 0) {
        a0.x += eq.x; a0.y += eq.y; a0.z += eq.z; a0.w += eq.w;
        t0 += 1.0f;
      } else {
        float4 s4 = *(const float4*)&ssw4[i * 4];
        a0.x += s4.x * eq.x; a0.y += s4.x * eq.y; a0.z += s4.x * eq.z; a0.w += s4.x * eq.w;
        a1.x += s4.y * eq.x; a1.y += s4.y * eq.y; a1.z += s4.y * eq.z; a1.w += s4.y * eq.w;
        a2.x += s4.z * eq.x; a2.y += s4.z * eq.y; a2.z += s4.z * eq.z; a2.w += s4.z * eq.w;
        a3.x += s4.w * eq.x; a3.y += s4.w * eq.y; a3.z += s4.w * eq.z; a3.w += s4.w * eq.w;
        t0 += s4.x; t1 += s4.y; t2 += s4.z; t3 += s4.w;
      }
    }
    RED_GRP(a0.x) RED_GRP(a0.y) RED_GRP(a0.z) RED_GRP(a0.w) RED_GRP(t0)
    if (it > 0) {
      RED_GRP(a1.x) RED_GRP(a1.y) RED_GRP(a1.z) RED_GRP(a1.w)
      RED_GRP(a2.x) RED_GRP(a2.y) RED_GRP(a2.z) RED_GRP(a2.w)
      RED_GRP(a3.x) RED_GRP(a3.y) RED_GRP(a3.z) RED_GRP(a3.w)
      RED_GRP(t1) RED_GRP(t2) RED_GRP(t3)
    } else {
      a0.x *= 0.25f; a0.y *= 0.25f; a0.z *= 0.25f; a0.w *= 0.25f;
      t0 *= 0.25f;
      a1 = a0; a2 = a0; a3 = a0; t1 = t0; t2 = t0; t3 = t0;
    }
    if (l < 16) {
      *(float4*)&pe[w][0][4 * l] = a0;
      *(float4*)&pe[w][1][4 * l] = a1;
      *(float4*)&pe[w][2][4 * l] = a2;
      *(float4*)&pe[w][3][4 * l] = a3;
    }
    if (l == 0) { pts[w][0] = t0; pts[w][1] = t1; pts[w][2] = t2; pts[w][3] = t3; }
    __syncthreads();

    // ---- E1: wave (k,h) reduces ITS OWN half of pe (no extra barrier),
    //      then dots with wreg ----
    {
      int cl = 32 * h_ + (l & 31);
      float sse = 0.f;
#pragma unroll
      for (int w2 = 0; w2 < 8; ++w2) sse += pe[w2][k_][cl];
      se[k_][cl] = sse;  // same-wave write -> broadcast read below
      float vp = 0.f;
#pragma unroll
      for (int q2 = 0; q2 < 8; ++q2) {
        float4 e4 = *(const float4*)&se[k_][32 * h_ + 4 * q2];  // broadcast
        vp += e4.x * wreg[4 * q2 + 0] + e4.y * wreg[4 * q2 + 1] +
              e4.z * wreg[4 * q2 + 2] + e4.w * wreg[4 * q2 + 3];
      }
      if (h_) pv[k_][l] = vp;
      __syncthreads();

      // ---- E2 (waves 0-3): combine halves, squash, update G / emit ----
      if (h_ == 0) {
        float ts_ = 0.f;
#pragma unroll
        for (int w2 = 0; w2 < 8; ++w2) ts_ += pts[w2][k_];
        float accv = vp + pv[k_][l] + ts_ * breg;
        float n2 = wred64(accv * accv);
        float scale = n2 / (1.f + n2) / sqrtf(n2 + 1e-9f);
        float inter = scale * accv;
        if (it < 2) {
          sG[k_][l] = (it == 0) ? inter : (sG[k_][l] + inter);
        } else {
          out[((size_t)b * NK + k_) * ND + l] = inter;
          float dot_ = wred64(inter * iq);
          pv[k_][l] = inter;  // stash for argmax gather
          if (l == 0) satt[k_] = dot_;
        }
      }
      __syncthreads();
    }
  }

  // ---- readout: first-max argmax (== np.argmax) + gather ----
  if (t == 0) {
    int bi = 0;
    float bv = satt[0];
#pragma unroll
    for (int kk = 1; kk < NK; ++kk)
      if (satt[kk] > bv) { bv = satt[kk]; bi = kk; }
    sidx = bi;
  }
  __syncthreads();
  if (t < ND) out[(size_t)NB * NK * ND + (size_t)b * ND + t] = pv[sidx][t];
}

extern "C" void kernel_launch(void* const* d_in, const int* in_sizes, int n_in,
                              void* d_out, int out_size, void* d_ws, size_t ws_size,
                              hipStream_t stream) {
  (void)in_sizes; (void)n_in; (void)out_size; (void)d_ws; (void)ws_size;
  const float* his = (const float*)d_in[0];
  const float* itemeb = (const float*)d_in[1];
  const int* mask = (const int*)d_in[2];
  const float* W = (const float*)d_in[3];
  const float* bias = (const float*)d_in[4];
  float* out = (float*)d_out;
  caps_kernel<<<NB, NT, 0, stream>>>(his, itemeb, mask, W, bias, out);
}

// Round 7
// 112.328 us; speedup vs baseline: 2.7631x; 2.7631x over previous
//
#include <hip/hip_runtime.h>

// CapsuleNetwork routing, fused, one block per batch. B=2048, S=200, D=64, K=4.
//
// hat[b,k,s,:] = emb[b,s,:] @ W_k + b_k is never materialized:
//   logits[k,s] = emb[s]·u[k] + off[k],  u[k] = W_k @ G[k], off[k] = b_k·G[k]
//   v[k]        = e[k] @ W_k + ts[k]·b_k, e[k] = sum_s sw[k,s] emb[s]
// G = running sum of interests (cw telescopes).
//
// Round-7 = round-4 MEMORY structure, exactly (full 200-row staging with
// identical global addresses, ~63KB LDS -> 2 blocks/CU; wreg W-cache;
// rounds 5/6 proved the compacted-staging + 3-blocks/CU bundle explodes
// FETCH 53->358MB) + compaction applied ONLY to the B/D sweep domain:
// masked rows have sw==0 exactly and contribute nothing, so B/D iterate
// just the ~100 active compact indices (sidxs), with ssw4 zero-padded to
// a 32-multiple so D's trip count stays wave-uniform. HBM pattern is
// byte-identical to round 4; LDS/VALU work in B/D halves.

#define NB 2048
#define NS 200
#define ND 64
#define NK 4
#define NT 512

__device__ __forceinline__ float wred64(float v) {
#pragma unroll
  for (int o = 1; o < 64; o <<= 1) v += __shfl_xor(v, o, 64);
  return v;
}

__device__ __forceinline__ void gload16(const float* g_, float* l_) {
  __builtin_amdgcn_global_load_lds(
      (const __attribute__((address_space(1))) unsigned int*)g_,
      (__attribute__((address_space(3))) unsigned int*)l_, 16, 0, 0);
}

#define RED_GRP(v) v += __shfl_xor(v, 16, 64); v += __shfl_xor(v, 32, 64);

__global__ __launch_bounds__(NT, 4) void caps_kernel(
    const float* __restrict__ his, const float* __restrict__ itemeb,
    const int* __restrict__ mask, const float* __restrict__ W,
    const float* __restrict__ bias, float* __restrict__ out) {
  __shared__ float semb[NS * ND];   // 51200B: row s, chunk c at slot (c+s)&15
  __shared__ float upool[2048];     // 8192B union: ssw4[<=224][4] | pe[8][4][64]
  __shared__ float pv[NK][ND];      // E h1 partials; final interest stash
  __shared__ float sG[NK][ND];      // running interest sum
  __shared__ float su[NK][ND];      // u[k]
  __shared__ unsigned short sidxs[NS];  // compact index -> original row s
  __shared__ int swofs[8];
  __shared__ float pts[8][NK];
  __shared__ float soff[NK], satt[NK];
  __shared__ int sidx;
  // total ~63.1 KB -> 2 blocks/CU (same residency as round 4)

  const int t = threadIdx.x;
  const int w = t >> 6, l = t & 63;
  const int g = l >> 4, j = l & 15;  // 16-lane group / chunk
  const int gid = (w << 2) | g;      // 0..31
  const int k_ = w & 3, h_ = w >> 2;
  const int b = blockIdx.x;
  const float* eb = his + (size_t)b * NS * ND;

  // ---- W slice in regs: wave (k,h) owns W[32h..32h+32)[64k+l] ----
  float wreg[32];
#pragma unroll
  for (int c = 0; c < 32; ++c)
    wreg[c] = W[(size_t)(32 * h_ + c) * (NK * ND) + k_ * ND + l];
  float breg = bias[k_ * ND + l];
  float iq = itemeb[(size_t)b * ND + l];

  // ---- stage ALL 200 rows — byte-identical addresses to round 4 ----
  for (int i = w; i < 50; i += 8) {
    int s = 4 * i + g;       // consecutive rows
    int q = (j - s) & 15;    // global chunk that lands at slot j
    gload16(eb + (s << 6) + (q << 2), &semb[i * 256]);
  }

  // ---- compaction of the SWEEP DOMAIN only (not of memory) ----
  int m = (t < NS) ? (mask[b * NS + t] != 0) : 0;
  unsigned long long bal = __ballot(m);
  int pre = __popcll(bal & ((1ull << l) - 1));
  if (l == 0) swofs[w] = __popcll(bal);
  __syncthreads();
  int base = 0, nact = 0;
#pragma unroll
  for (int ww = 0; ww < 8; ++ww) {
    base += (ww < w) ? swofs[ww] : 0;
    nact += swofs[ww];
  }
  if (m) sidxs[base + pre] = (unsigned short)t;
  const int nactp = (nact + 31) & ~31;  // wave-uniform D trip count
  // init sw(it=0) = 0.25 (softmax of zeros over K) on active rows, 0 on pad
  if (t < nactp) {
    float v = (t < nact) ? 0.25f : 0.0f;
    *(float4*)&upool[t * 4] = make_float4(v, v, v, v);
  }
  __syncthreads();

  for (int it = 0; it < 3; ++it) {
    if (it > 0) {
      // ---- A: waves 0-3: su[w][l] = W-row-l(cols 64w..) . G[w];
      //         waves 4-7: soff[w-4] = b . G ----
      if (w < 4) {
        const float4* Wr = (const float4*)(W + (size_t)l * (NK * ND) + w * ND);
        const float4* Gk = (const float4*)&sG[w][0];  // broadcast
        float a = 0.f;
#pragma unroll
        for (int d4 = 0; d4 < 16; ++d4) {
          float4 wv = Wr[d4], gv = Gk[d4];
          a += wv.x * gv.x + wv.y * gv.y + wv.z * gv.z + wv.w * gv.w;
        }
        su[w][l] = a;
      } else {
        float ob = wred64(breg * sG[w - 4][l]);  // breg IS bias[(w-4)*64+l]
        if (l == 0) soff[w - 4] = ob;
      }
      __syncthreads();

      // ---- B: thread-per-ACTIVE-row; in-lane softmax over k ----
      if (t < nact) {
        int srow = sidxs[t];
        float lg0 = soff[0], lg1 = soff[1], lg2 = soff[2], lg3 = soff[3];
#pragma unroll
        for (int jj = 0; jj < 16; ++jj) {
          float4 eq =
              *(const float4*)&semb[(srow << 6) + 4 * ((jj + srow) & 15)];
          float4 u0 = *(const float4*)&su[0][4 * jj];  // broadcast reads
          float4 u1 = *(const float4*)&su[1][4 * jj];
          float4 u2 = *(const float4*)&su[2][4 * jj];
          float4 u3 = *(const float4*)&su[3][4 * jj];
          lg0 += eq.x * u0.x + eq.y * u0.y + eq.z * u0.z + eq.w * u0.w;
          lg1 += eq.x * u1.x + eq.y * u1.y + eq.z * u1.z + eq.w * u1.w;
          lg2 += eq.x * u2.x + eq.y * u2.y + eq.z * u2.z + eq.w * u2.w;
          lg3 += eq.x * u3.x + eq.y * u3.y + eq.z * u3.z + eq.w * u3.w;
        }
        float mx = fmaxf(fmaxf(lg0, lg1), fmaxf(lg2, lg3));
        float e0 = __expf(lg0 - mx), e1 = __expf(lg1 - mx);
        float e2 = __expf(lg2 - mx), e3 = __expf(lg3 - mx);
        float r = 1.0f / (e0 + e1 + e2 + e3);  // active rows: mask == 1
        *(float4*)&upool[t * 4] = make_float4(e0 * r, e1 * r, e2 * r, e3 * r);
      } else if (t < nactp) {
        *(float4*)&upool[t * 4] = make_float4(0.f, 0.f, 0.f, 0.f);
      }
      __syncthreads();
    }

    // ---- D: group gid sweeps compact i = gid + 32*tt (uniform trips) ----
    float4 a0 = {0, 0, 0, 0}, a1 = {0, 0, 0, 0}, a2 = {0, 0, 0, 0},
           a3 = {0, 0, 0, 0};
    float t0 = 0, t1 = 0, t2 = 0, t3 = 0;
    for (int i = gid; i < nactp; i += 32) {
      int srow = (i < nact) ? (int)sidxs[i] : 0;  // clamp pad (weight 0)
      float4 eq = *(const float4*)&semb[(srow << 6) + 4 * ((j + srow) & 15)];
      float4 s4 = *(const float4*)&upool[i * 4];  // broadcast
      a0.x += s4.x * eq.x; a0.y += s4.x * eq.y; a0.z += s4.x * eq.z; a0.w += s4.x * eq.w;
      a1.x += s4.y * eq.x; a1.y += s4.y * eq.y; a1.z += s4.y * eq.z; a1.w += s4.y * eq.w;
      a2.x += s4.z * eq.x; a2.y += s4.z * eq.y; a2.z += s4.z * eq.z; a2.w += s4.z * eq.w;
      a3.x += s4.w * eq.x; a3.y += s4.w * eq.y; a3.z += s4.w * eq.z; a3.w += s4.w * eq.w;
      t0 += s4.x; t1 += s4.y; t2 += s4.z; t3 += s4.w;
    }
    __syncthreads();  // all ssw reads done before pe overwrites the pool

    RED_GRP(a0.x) RED_GRP(a0.y) RED_GRP(a0.z) RED_GRP(a0.w)
    RED_GRP(a1.x) RED_GRP(a1.y) RED_GRP(a1.z) RED_GRP(a1.w)
    RED_GRP(a2.x) RED_GRP(a2.y) RED_GRP(a2.z) RED_GRP(a2.w)
    RED_GRP(a3.x) RED_GRP(a3.y) RED_GRP(a3.z) RED_GRP(a3.w)
    RED_GRP(t0) RED_GRP(t1) RED_GRP(t2) RED_GRP(t3)
    if (l < 16) {
      *(float4*)&upool[w * 256 + 0 + 4 * l] = a0;    // pe[w][0][..]
      *(float4*)&upool[w * 256 + 64 + 4 * l] = a1;   // pe[w][1][..]
      *(float4*)&upool[w * 256 + 128 + 4 * l] = a2;  // pe[w][2][..]
      *(float4*)&upool[w * 256 + 192 + 4 * l] = a3;  // pe[w][3][..]
    }
    if (l == 0) { pts[w][0] = t0; pts[w][1] = t1; pts[w][2] = t2; pts[w][3] = t3; }
    __syncthreads();

    // ---- E1: wave (k,h) dots pe partials with wreg directly (broadcast) ----
    float vp = 0.f;
#pragma unroll
    for (int w2 = 0; w2 < 8; ++w2) {
#pragma unroll
      for (int q2 = 0; q2 < 8; ++q2) {
        float4 e4 =
            *(const float4*)&upool[w2 * 256 + k_ * 64 + 32 * h_ + 4 * q2];
        vp += e4.x * wreg[4 * q2 + 0] + e4.y * wreg[4 * q2 + 1] +
              e4.z * wreg[4 * q2 + 2] + e4.w * wreg[4 * q2 + 3];
      }
    }
    if (h_) pv[k_][l] = vp;
    __syncthreads();

    // ---- E2 (waves 0-3): combine halves, squash, update G / emit ----
    if (h_ == 0) {
      float ts_ = 0.f;
#pragma unroll
      for (int w2 = 0; w2 < 8; ++w2) ts_ += pts[w2][k_];
      float accv = vp + pv[k_][l] + ts_ * breg;
      float n2 = wred64(accv * accv);
      float scale = n2 / (1.f + n2) / sqrtf(n2 + 1e-9f);
      float inter = scale * accv;
      if (it < 2) {
        sG[k_][l] = (it == 0) ? inter : (sG[k_][l] + inter);
      } else {
        out[((size_t)b * NK + k_) * ND + l] = inter;
        float dot_ = wred64(inter * iq);
        pv[k_][l] = inter;  // stash for argmax gather
        if (l == 0) satt[k_] = dot_;
      }
    }
    __syncthreads();
  }

  // ---- readout: first-max argmax (== np.argmax) + gather ----
  if (t == 0) {
    int bi = 0;
    float bv = satt[0];
#pragma unroll
    for (int kk = 1; kk < NK; ++kk)
      if (satt[kk] > bv) { bv = satt[kk]; bi = kk; }
    sidx = bi;
  }
  __syncthreads();
  if (t < ND) out[(size_t)NB * NK * ND + (size_t)b * ND + t] = pv[sidx][t];
}

extern "C" void kernel_launch(void* const* d_in, const int* in_sizes, int n_in,
                              void* d_out, int out_size, void* d_ws, size_t ws_size,
                              hipStream_t stream) {
  (void)in_sizes; (void)n_in; (void)out_size; (void)d_ws; (void)ws_size;
  const float* his = (const float*)d_in[0];
  const float* itemeb = (const float*)d_in[1];
  const int* mask = (const int*)d_in[2];
  const float* W = (const float*)d_in[3];
  const float* bias = (const float*)d_in[4];
  float* out = (float*)d_out;
  caps_kernel<<<NB, NT, 0, stream>>>(his, itemeb, mask, W, bias, out);
}